// Round 4
// baseline (912.013 us; speedup 1.0000x reference)
//
#include <hip/hip_runtime.h>
#include <cfloat>

#define N_NODES 50000
#define N_EDGES 1600000
#define ET      (N_EDGES + N_NODES)   // with self loops
#define DX      128
#define DH      64
#define KH      4
#define NC      256                   // KH*DH
#define NEG_SLOPE 0.01f

// ---------- setup: zero cnt/colsum + transpose Ww (256x128)->Wt(128x256) ----------
__global__ void k_setup(const float* __restrict__ Ww, float* __restrict__ Wt,
                        int* __restrict__ cnt, float* __restrict__ colsum) {
    int i = blockIdx.x * 256 + threadIdx.x;
    if (i < N_NODES) cnt[i] = 0;
    if (i < NC) colsum[i] = 0.f;
    if (i < DX * NC) {
        int d = i >> 8, c = i & 255;
        Wt[d * NC + c] = Ww[c * DX + d];
    }
}

__device__ __forceinline__ unsigned pack_bf16(float a, float b) {
    unsigned ua = __float_as_uint(a), ub = __float_as_uint(b);
    ua = (ua + 0x7FFFu + ((ua >> 16) & 1u)) >> 16;          // RNE
    ub = (ub + 0x7FFFu + ((ub >> 16) & 1u)) & 0xFFFF0000u;
    return ua | ub;
}

// ---------- Wx GEMM + fused si/sj epilogue; writes bf16 copy for the gather ----------
__global__ void __launch_bounds__(256) k_gemm1(const float* __restrict__ x,
                                               const float* __restrict__ Wt,
                                               const float* __restrict__ Wb,
                                               const float* __restrict__ aw,
                                               const float* __restrict__ ab,
                                               uint2* __restrict__ Wxb,
                                               float* __restrict__ sic,
                                               float* __restrict__ sjc) {
    int wave = blockIdx.x * 4 + (threadIdx.x >> 6);
    if (wave >= N_NODES / 8) return;           // 50000 % 8 == 0
    int lane = threadIdx.x & 63;
    int kh = lane >> 4, lq = lane & 15;
    int n0 = wave * 8;
    const float4* WtV = (const float4*)Wt;
    float acc[8][4];
#pragma unroll
    for (int r = 0; r < 8; ++r)
#pragma unroll
        for (int q = 0; q < 4; ++q) acc[r][q] = 0.f;

    for (int d = 0; d < DX; d += 4) {
        float xr[8][4];
#pragma unroll
        for (int r = 0; r < 8; ++r) {
            float4 v = *(const float4*)&x[(size_t)(n0 + r) * DX + d];
            xr[r][0] = v.x; xr[r][1] = v.y; xr[r][2] = v.z; xr[r][3] = v.w;
        }
#pragma unroll
        for (int q = 0; q < 4; ++q) {
            float4 wv = WtV[(size_t)(d + q) * 64 + lane];
#pragma unroll
            for (int r = 0; r < 8; ++r) {
                acc[r][0] += xr[r][q] * wv.x;
                acc[r][1] += xr[r][q] * wv.y;
                acc[r][2] += xr[r][q] * wv.z;
                acc[r][3] += xr[r][q] * wv.w;
            }
        }
    }
    float4 bias = ((const float4*)Wb)[lane];
    const float* awi = aw + kh * 2 * DH + lq * 4;
    const float* awj = awi + DH;
    float ai0 = awi[0], ai1 = awi[1], ai2 = awi[2], ai3 = awi[3];
    float aj0 = awj[0], aj1 = awj[1], aj2 = awj[2], aj3 = awj[3];
    float abk = ab[kh];
#pragma unroll
    for (int r = 0; r < 8; ++r) {
        float o0 = acc[r][0] + bias.x, o1 = acc[r][1] + bias.y;
        float o2 = acc[r][2] + bias.z, o3 = acc[r][3] + bias.w;
        uint2 pk; pk.x = pack_bf16(o0, o1); pk.y = pack_bf16(o2, o3);
        Wxb[(size_t)(n0 + r) * 64 + lane] = pk;
        float pi = o0 * ai0 + o1 * ai1 + o2 * ai2 + o3 * ai3;
        float pj = o0 * aj0 + o1 * aj1 + o2 * aj2 + o3 * aj3;
#pragma unroll
        for (int off = 8; off >= 1; off >>= 1) {
            pi += __shfl_xor(pi, off, 64);
            pj += __shfl_xor(pj, off, 64);
        }
        if (lq == 0) {
            sic[(n0 + r) * 4 + kh] = pi + abk;   // fold ab into dst-side score
            sjc[(n0 + r) * 4 + kh] = pj;
        }
    }
}

// ---------- CSR build (edge_index is int32 from harness) ----------
__global__ void k_hist(const int* __restrict__ ei, int* __restrict__ cnt) {
    int stride = gridDim.x * blockDim.x;
    for (int e = blockIdx.x * blockDim.x + threadIdx.x; e < ET; e += stride) {
        int dst = (e < N_EDGES) ? ei[N_EDGES + e] : (e - N_EDGES);
        atomicAdd(&cnt[dst], 1);
    }
}

__global__ void __launch_bounds__(1024) k_scan(const int* __restrict__ cnt,
                                               int* __restrict__ rowstart,
                                               int* __restrict__ cursor) {
    __shared__ int sums[1024];
    int t = threadIdx.x;
    const int chunk = (N_NODES + 1023) / 1024;
    int s0 = t * chunk, s1 = min(s0 + chunk, N_NODES);
    int s = 0;
    for (int i = s0; i < s1; ++i) s += cnt[i];
    sums[t] = s;
    __syncthreads();
    for (int off = 1; off < 1024; off <<= 1) {
        int v = (t >= off) ? sums[t - off] : 0;
        __syncthreads();
        sums[t] += v;
        __syncthreads();
    }
    int run = (t == 0) ? 0 : sums[t - 1];
    for (int i = s0; i < s1; ++i) {
        rowstart[i] = run; cursor[i] = run; run += cnt[i];
    }
    if (t == 1023) rowstart[N_NODES] = sums[1023];
}

__global__ void k_scatter(const int* __restrict__ ei, int* __restrict__ cursor,
                          int* __restrict__ csr_src) {
    int stride = gridDim.x * blockDim.x;
    for (int e = blockIdx.x * blockDim.x + threadIdx.x; e < ET; e += stride) {
        int src, dst;
        if (e < N_EDGES) { src = ei[e]; dst = ei[N_EDGES + e]; }
        else { src = dst = e - N_EDGES; }
        int pos = atomicAdd(&cursor[dst], 1);
        csr_src[pos] = src;
    }
}

// ---------- aggregation, software-pipelined x8, + fused colsum partial ----------
__device__ __forceinline__ void edge_acc(unsigned gx, unsigned gy, float t, float sval,
                                         float& den, float& a0, float& a1, float& a2, float& a3) {
    float e = sval + t;
    e = (e >= 0.f) ? e : NEG_SLOPE * e;
    float ex = __expf(e);
    den += ex;
    a0 += ex * __uint_as_float(gx << 16);
    a1 += ex * __uint_as_float(gx & 0xFFFF0000u);
    a2 += ex * __uint_as_float(gy << 16);
    a3 += ex * __uint_as_float(gy & 0xFFFF0000u);
}

__global__ void __launch_bounds__(256) k_aggregate(const int* __restrict__ rowstart,
                                                   const int* __restrict__ csr_src,
                                                   const float* __restrict__ sic,
                                                   const float* __restrict__ sjc,
                                                   const uint2* __restrict__ Wxb,
                                                   float* __restrict__ expagg,
                                                   float* __restrict__ colsum) {
    __shared__ float red[4][NC];
    int widx = threadIdx.x >> 6;
    int dst = blockIdx.x * 4 + widx;     // grid = 12500, exact
    int lane = threadIdx.x & 63;
    int kh = lane >> 4;
    int i0 = rowstart[dst], i1 = rowstart[dst + 1];
    float sval = sic[dst * 4 + kh];

    float den = 0.f, a0 = 0.f, a1 = 0.f, a2 = 0.f, a3 = 0.f;
    int i = i0;
    for (; i + 8 <= i1; i += 8) {
        int s0 = csr_src[i];     int s1 = csr_src[i + 1];
        int s2 = csr_src[i + 2]; int s3 = csr_src[i + 3];
        int s4 = csr_src[i + 4]; int s5 = csr_src[i + 5];
        int s6 = csr_src[i + 6]; int s7 = csr_src[i + 7];
        uint2 g0 = Wxb[(size_t)s0 * 64 + lane];
        uint2 g1 = Wxb[(size_t)s1 * 64 + lane];
        uint2 g2 = Wxb[(size_t)s2 * 64 + lane];
        uint2 g3 = Wxb[(size_t)s3 * 64 + lane];
        uint2 g4 = Wxb[(size_t)s4 * 64 + lane];
        uint2 g5 = Wxb[(size_t)s5 * 64 + lane];
        uint2 g6 = Wxb[(size_t)s6 * 64 + lane];
        uint2 g7 = Wxb[(size_t)s7 * 64 + lane];
        float t0 = sjc[s0 * 4 + kh]; float t1 = sjc[s1 * 4 + kh];
        float t2 = sjc[s2 * 4 + kh]; float t3 = sjc[s3 * 4 + kh];
        float t4 = sjc[s4 * 4 + kh]; float t5 = sjc[s5 * 4 + kh];
        float t6 = sjc[s6 * 4 + kh]; float t7 = sjc[s7 * 4 + kh];
        edge_acc(g0.x, g0.y, t0, sval, den, a0, a1, a2, a3);
        edge_acc(g1.x, g1.y, t1, sval, den, a0, a1, a2, a3);
        edge_acc(g2.x, g2.y, t2, sval, den, a0, a1, a2, a3);
        edge_acc(g3.x, g3.y, t3, sval, den, a0, a1, a2, a3);
        edge_acc(g4.x, g4.y, t4, sval, den, a0, a1, a2, a3);
        edge_acc(g5.x, g5.y, t5, sval, den, a0, a1, a2, a3);
        edge_acc(g6.x, g6.y, t6, sval, den, a0, a1, a2, a3);
        edge_acc(g7.x, g7.y, t7, sval, den, a0, a1, a2, a3);
    }
    for (; i < i1; ++i) {
        int s = csr_src[i];
        uint2 g = Wxb[(size_t)s * 64 + lane];
        float t = sjc[s * 4 + kh];
        edge_acc(g.x, g.y, t, sval, den, a0, a1, a2, a3);
    }
    float r = 1.f / den;
    float4 o;
    o.x = __expf(a0 * r); o.y = __expf(a1 * r);
    o.z = __expf(a2 * r); o.w = __expf(a3 * r);
    ((float4*)expagg)[(size_t)dst * 64 + lane] = o;

    // fused colsum partial: reduce 4 waves' rows, one atomicAdd per column
    ((float4*)&red[widx][0])[lane] = o;
    __syncthreads();
    int t = threadIdx.x;
    float s = red[0][t] + red[1][t] + red[2][t] + red[3][t];
    atomicAdd(&colsum[t], s);
}

// ---------- Ws[c][j] = Wo_w[j][c] / colsum[c] ----------
__global__ void k_prepWs(const float* __restrict__ Wo_w, const float* __restrict__ colsum,
                         float* __restrict__ Ws) {
    int i = blockIdx.x * 256 + threadIdx.x;   // 16384 total
    int c = i >> 6, j = i & 63;
    Ws[c * 64 + j] = Wo_w[j * NC + c] / colsum[c];
}

// ---------- out[n][j] = sum_c expagg[n][c] * Ws[c][j] + Wo_b[j] ----------
__global__ void __launch_bounds__(256) k_out(const float* __restrict__ expagg,
                                             const float* __restrict__ Ws,
                                             const float* __restrict__ Wo_b,
                                             float* __restrict__ out) {
    int wave = blockIdx.x * 4 + (threadIdx.x >> 6);
    if (wave >= N_NODES / 8) return;
    int j = threadIdx.x & 63;
    int n0 = wave * 8;
    float acc[8];
#pragma unroll
    for (int r = 0; r < 8; ++r) acc[r] = 0.f;
    for (int c = 0; c < NC; c += 4) {
        float w0 = Ws[c * 64 + j];
        float w1 = Ws[(c + 1) * 64 + j];
        float w2 = Ws[(c + 2) * 64 + j];
        float w3 = Ws[(c + 3) * 64 + j];
#pragma unroll
        for (int r = 0; r < 8; ++r) {
            float4 v = *(const float4*)&expagg[(size_t)(n0 + r) * NC + c];
            acc[r] += v.x * w0 + v.y * w1 + v.z * w2 + v.w * w3;
        }
    }
    float b = Wo_b[j];
#pragma unroll
    for (int r = 0; r < 8; ++r)
        out[(size_t)(n0 + r) * DH + j] = acc[r] + b;
}

extern "C" void kernel_launch(void* const* d_in, const int* in_sizes, int n_in,
                              void* d_out, int out_size, void* d_ws, size_t ws_size,
                              hipStream_t stream) {
    const int*   ei   = (const int*)d_in[0];     // int32 from harness
    const float* x    = (const float*)d_in[1];
    const float* Ww   = (const float*)d_in[2];
    const float* Wb   = (const float*)d_in[3];
    const float* aw   = (const float*)d_in[4];
    const float* ab   = (const float*)d_in[5];
    const float* Wo_w = (const float*)d_in[6];
    const float* Wo_b = (const float*)d_in[7];
    float* out = (float*)d_out;

    char* p = (char*)d_ws;
    auto alloc = [&](size_t bytes) -> char* {
        char* q = p;
        p += (bytes + 255) & ~(size_t)255;
        return q;
    };
    uint2*    Wxb      = (uint2*)alloc((size_t)N_NODES * NC * 2);   // bf16 copy
    float*    expagg   = (float*)alloc((size_t)N_NODES * NC * 4);
    float*    Wt       = (float*)alloc((size_t)DX * NC * 4);
    float*    sic      = (float*)alloc((size_t)N_NODES * 4 * 4);
    float*    sjc      = (float*)alloc((size_t)N_NODES * 4 * 4);
    int*      cnt      = (int*)alloc((size_t)N_NODES * 4);
    int*      rowstart = (int*)alloc((size_t)(N_NODES + 1) * 4);
    int*      cursor   = (int*)alloc((size_t)N_NODES * 4);
    int*      csr_src  = (int*)alloc((size_t)ET * 4);
    float*    colsum   = (float*)alloc(NC * 4);
    float*    Ws       = (float*)alloc(NC * DH * 4);

    k_setup<<<(N_NODES + 255) / 256, 256, 0, stream>>>(Ww, Wt, cnt, colsum);
    k_gemm1<<<(N_NODES / 8 + 3) / 4, 256, 0, stream>>>(x, Wt, Wb, aw, ab, Wxb, sic, sjc);
    k_hist<<<2048, 256, 0, stream>>>(ei, cnt);
    k_scan<<<1, 1024, 0, stream>>>(cnt, rowstart, cursor);
    k_scatter<<<2048, 256, 0, stream>>>(ei, cursor, csr_src);
    k_aggregate<<<N_NODES / 4, 256, 0, stream>>>(rowstart, csr_src, sic, sjc, Wxb, expagg, colsum);
    k_prepWs<<<(NC * DH) / 256, 256, 0, stream>>>(Wo_w, colsum, Ws);
    k_out<<<(N_NODES / 8 + 3) / 4, 256, 0, stream>>>(expagg, Ws, Wo_b, out);
}

// Round 5
// 755.696 us; speedup vs baseline: 1.2069x; 1.2069x over previous
//
#include <hip/hip_runtime.h>
#include <cfloat>

#define N_NODES 50000
#define N_EDGES 1600000
#define DX      128
#define DH      64
#define KH      4
#define NC      256                   // KH*DH
#define NEG_SLOPE 0.01f

// ---------- setup: cnt=1 (self-loop pre-count), zero colsum, transpose Ww ----------
__global__ void k_setup(const float* __restrict__ Ww, float* __restrict__ Wt,
                        int* __restrict__ cnt, float* __restrict__ colsum) {
    int i = blockIdx.x * 256 + threadIdx.x;
    if (i < N_NODES) cnt[i] = 1;               // every node gets one self-loop
    if (i < NC) colsum[i] = 0.f;
    if (i < DX * NC) {
        int d = i >> 8, c = i & 255;
        Wt[d * NC + c] = Ww[c * DX + d];
    }
}

__device__ __forceinline__ unsigned pack_bf16(float a, float b) {
    unsigned ua = __float_as_uint(a), ub = __float_as_uint(b);
    ua = (ua + 0x7FFFu + ((ua >> 16) & 1u)) >> 16;          // RNE
    ub = (ub + 0x7FFFu + ((ub >> 16) & 1u)) & 0xFFFF0000u;
    return ua | ub;
}

// ---------- Wx GEMM + fused si/sj epilogue; writes bf16 copy for the gather ----------
__global__ void __launch_bounds__(256) k_gemm1(const float* __restrict__ x,
                                               const float* __restrict__ Wt,
                                               const float* __restrict__ Wb,
                                               const float* __restrict__ aw,
                                               const float* __restrict__ ab,
                                               uint2* __restrict__ Wxb,
                                               float* __restrict__ sic,
                                               float* __restrict__ sjc) {
    int wave = blockIdx.x * 4 + (threadIdx.x >> 6);
    if (wave >= N_NODES / 8) return;           // 50000 % 8 == 0
    int lane = threadIdx.x & 63;
    int kh = lane >> 4, lq = lane & 15;
    int n0 = wave * 8;
    const float4* WtV = (const float4*)Wt;
    float acc[8][4];
#pragma unroll
    for (int r = 0; r < 8; ++r)
#pragma unroll
        for (int q = 0; q < 4; ++q) acc[r][q] = 0.f;

    for (int d = 0; d < DX; d += 4) {
        float xr[8][4];
#pragma unroll
        for (int r = 0; r < 8; ++r) {
            float4 v = *(const float4*)&x[(size_t)(n0 + r) * DX + d];
            xr[r][0] = v.x; xr[r][1] = v.y; xr[r][2] = v.z; xr[r][3] = v.w;
        }
#pragma unroll
        for (int q = 0; q < 4; ++q) {
            float4 wv = WtV[(size_t)(d + q) * 64 + lane];
#pragma unroll
            for (int r = 0; r < 8; ++r) {
                acc[r][0] += xr[r][q] * wv.x;
                acc[r][1] += xr[r][q] * wv.y;
                acc[r][2] += xr[r][q] * wv.z;
                acc[r][3] += xr[r][q] * wv.w;
            }
        }
    }
    float4 bias = ((const float4*)Wb)[lane];
    const float* awi = aw + kh * 2 * DH + lq * 4;
    const float* awj = awi + DH;
    float ai0 = awi[0], ai1 = awi[1], ai2 = awi[2], ai3 = awi[3];
    float aj0 = awj[0], aj1 = awj[1], aj2 = awj[2], aj3 = awj[3];
    float abk = ab[kh];
#pragma unroll
    for (int r = 0; r < 8; ++r) {
        float o0 = acc[r][0] + bias.x, o1 = acc[r][1] + bias.y;
        float o2 = acc[r][2] + bias.z, o3 = acc[r][3] + bias.w;
        uint2 pk; pk.x = pack_bf16(o0, o1); pk.y = pack_bf16(o2, o3);
        Wxb[(size_t)(n0 + r) * 64 + lane] = pk;
        float pi = o0 * ai0 + o1 * ai1 + o2 * ai2 + o3 * ai3;
        float pj = o0 * aj0 + o1 * aj1 + o2 * aj2 + o3 * aj3;
#pragma unroll
        for (int off = 8; off >= 1; off >>= 1) {
            pi += __shfl_xor(pi, off, 64);
            pj += __shfl_xor(pj, off, 64);
        }
        if (lq == 0) {
            sic[(n0 + r) * 4 + kh] = pi + abk;   // fold ab into dst-side score
            sjc[(n0 + r) * 4 + kh] = pj;
        }
    }
}

// ---------- CSR build: real edges only (self loops pre-placed by k_scan) ----------
__global__ void k_hist(const int* __restrict__ ei, int* __restrict__ cnt) {
    const int4* dst4 = (const int4*)(ei + N_EDGES);
    int stride = gridDim.x * blockDim.x;
    for (int e = blockIdx.x * blockDim.x + threadIdx.x; e < N_EDGES / 4; e += stride) {
        int4 d = dst4[e];
        atomicAdd(&cnt[d.x], 1);
        atomicAdd(&cnt[d.y], 1);
        atomicAdd(&cnt[d.z], 1);
        atomicAdd(&cnt[d.w], 1);
    }
}

__global__ void __launch_bounds__(1024) k_scan(const int* __restrict__ cnt,
                                               int* __restrict__ rowstart,
                                               int* __restrict__ cursor,
                                               int* __restrict__ csr_src) {
    __shared__ int sums[1024];
    int t = threadIdx.x;
    const int chunk = (N_NODES + 1023) / 1024;
    int s0 = t * chunk, s1 = min(s0 + chunk, N_NODES);
    int s = 0;
    for (int i = s0; i < s1; ++i) s += cnt[i];
    sums[t] = s;
    __syncthreads();
    for (int off = 1; off < 1024; off <<= 1) {
        int v = (t >= off) ? sums[t - off] : 0;
        __syncthreads();
        sums[t] += v;
        __syncthreads();
    }
    int run = (t == 0) ? 0 : sums[t - 1];
    for (int i = s0; i < s1; ++i) {
        rowstart[i] = run;
        csr_src[run] = i;          // self-loop edge placed first
        cursor[i] = run + 1;
        run += cnt[i];
    }
    if (t == 1023) rowstart[N_NODES] = sums[1023];
}

__global__ void k_scatter(const int* __restrict__ ei, int* __restrict__ cursor,
                          int* __restrict__ csr_src) {
    const int4* src4 = (const int4*)ei;
    const int4* dst4 = (const int4*)(ei + N_EDGES);
    int stride = gridDim.x * blockDim.x;
    for (int e = blockIdx.x * blockDim.x + threadIdx.x; e < N_EDGES / 4; e += stride) {
        int4 sv = src4[e];
        int4 dv = dst4[e];
        csr_src[atomicAdd(&cursor[dv.x], 1)] = sv.x;
        csr_src[atomicAdd(&cursor[dv.y], 1)] = sv.y;
        csr_src[atomicAdd(&cursor[dv.z], 1)] = sv.z;
        csr_src[atomicAdd(&cursor[dv.w], 1)] = sv.w;
    }
}

// ---------- aggregation, software-pipelined x8, pure (no LDS/atomics) ----------
__device__ __forceinline__ void edge_acc(unsigned gx, unsigned gy, float t, float sval,
                                         float& den, float& a0, float& a1, float& a2, float& a3) {
    float e = sval + t;
    e = (e >= 0.f) ? e : NEG_SLOPE * e;
    float ex = __expf(e);
    den += ex;
    a0 += ex * __uint_as_float(gx << 16);
    a1 += ex * __uint_as_float(gx & 0xFFFF0000u);
    a2 += ex * __uint_as_float(gy << 16);
    a3 += ex * __uint_as_float(gy & 0xFFFF0000u);
}

__global__ void __launch_bounds__(256) k_aggregate(const int* __restrict__ rowstart,
                                                   const int* __restrict__ csr_src,
                                                   const float* __restrict__ sic,
                                                   const float* __restrict__ sjc,
                                                   const uint2* __restrict__ Wxb,
                                                   float* __restrict__ expagg) {
    int dst = blockIdx.x * 4 + (threadIdx.x >> 6);   // grid = 12500, exact
    int lane = threadIdx.x & 63;
    int kh = lane >> 4;
    int i0 = rowstart[dst], i1 = rowstart[dst + 1];
    float sval = sic[dst * 4 + kh];

    float den = 0.f, a0 = 0.f, a1 = 0.f, a2 = 0.f, a3 = 0.f;
    int i = i0;
    for (; i + 8 <= i1; i += 8) {
        int s0 = csr_src[i];     int s1 = csr_src[i + 1];
        int s2 = csr_src[i + 2]; int s3 = csr_src[i + 3];
        int s4 = csr_src[i + 4]; int s5 = csr_src[i + 5];
        int s6 = csr_src[i + 6]; int s7 = csr_src[i + 7];
        uint2 g0 = Wxb[(size_t)s0 * 64 + lane];
        uint2 g1 = Wxb[(size_t)s1 * 64 + lane];
        uint2 g2 = Wxb[(size_t)s2 * 64 + lane];
        uint2 g3 = Wxb[(size_t)s3 * 64 + lane];
        uint2 g4 = Wxb[(size_t)s4 * 64 + lane];
        uint2 g5 = Wxb[(size_t)s5 * 64 + lane];
        uint2 g6 = Wxb[(size_t)s6 * 64 + lane];
        uint2 g7 = Wxb[(size_t)s7 * 64 + lane];
        float t0 = sjc[s0 * 4 + kh]; float t1 = sjc[s1 * 4 + kh];
        float t2 = sjc[s2 * 4 + kh]; float t3 = sjc[s3 * 4 + kh];
        float t4 = sjc[s4 * 4 + kh]; float t5 = sjc[s5 * 4 + kh];
        float t6 = sjc[s6 * 4 + kh]; float t7 = sjc[s7 * 4 + kh];
        edge_acc(g0.x, g0.y, t0, sval, den, a0, a1, a2, a3);
        edge_acc(g1.x, g1.y, t1, sval, den, a0, a1, a2, a3);
        edge_acc(g2.x, g2.y, t2, sval, den, a0, a1, a2, a3);
        edge_acc(g3.x, g3.y, t3, sval, den, a0, a1, a2, a3);
        edge_acc(g4.x, g4.y, t4, sval, den, a0, a1, a2, a3);
        edge_acc(g5.x, g5.y, t5, sval, den, a0, a1, a2, a3);
        edge_acc(g6.x, g6.y, t6, sval, den, a0, a1, a2, a3);
        edge_acc(g7.x, g7.y, t7, sval, den, a0, a1, a2, a3);
    }
    for (; i < i1; ++i) {
        int s = csr_src[i];
        uint2 g = Wxb[(size_t)s * 64 + lane];
        float t = sjc[s * 4 + kh];
        edge_acc(g.x, g.y, t, sval, den, a0, a1, a2, a3);
    }
    float r = 1.f / den;
    float4 o;
    o.x = __expf(a0 * r); o.y = __expf(a1 * r);
    o.z = __expf(a2 * r); o.w = __expf(a3 * r);
    ((float4*)expagg)[(size_t)dst * 64 + lane] = o;
}

// ---------- column sums of exp(agg) ----------
__global__ void __launch_bounds__(256) k_colsum(const float* __restrict__ expagg,
                                                float* __restrict__ colsum) {
    int c = threadIdx.x;
    int r0 = blockIdx.x * 196;
    int r1 = min(r0 + 196, N_NODES);
    float s = 0.f;
    for (int r = r0; r < r1; ++r) s += expagg[(size_t)r * NC + c];
    atomicAdd(&colsum[c], s);
}

// ---------- Ws[c][j] = Wo_w[j][c] / colsum[c] ----------
__global__ void k_prepWs(const float* __restrict__ Wo_w, const float* __restrict__ colsum,
                         float* __restrict__ Ws) {
    int i = blockIdx.x * 256 + threadIdx.x;   // 16384 total
    int c = i >> 6, j = i & 63;
    Ws[c * 64 + j] = Wo_w[j * NC + c] / colsum[c];
}

// ---------- out[n][j] = sum_c expagg[n][c] * Ws[c][j] + Wo_b[j] ----------
__global__ void __launch_bounds__(256) k_out(const float* __restrict__ expagg,
                                             const float* __restrict__ Ws,
                                             const float* __restrict__ Wo_b,
                                             float* __restrict__ out) {
    int wave = blockIdx.x * 4 + (threadIdx.x >> 6);
    if (wave >= N_NODES / 8) return;
    int j = threadIdx.x & 63;
    int n0 = wave * 8;
    float acc[8];
#pragma unroll
    for (int r = 0; r < 8; ++r) acc[r] = 0.f;
    for (int c = 0; c < NC; c += 4) {
        float w0 = Ws[c * 64 + j];
        float w1 = Ws[(c + 1) * 64 + j];
        float w2 = Ws[(c + 2) * 64 + j];
        float w3 = Ws[(c + 3) * 64 + j];
#pragma unroll
        for (int r = 0; r < 8; ++r) {
            float4 v = *(const float4*)&expagg[(size_t)(n0 + r) * NC + c];
            acc[r] += v.x * w0 + v.y * w1 + v.z * w2 + v.w * w3;
        }
    }
    float b = Wo_b[j];
#pragma unroll
    for (int r = 0; r < 8; ++r)
        out[(size_t)(n0 + r) * DH + j] = acc[r] + b;
}

extern "C" void kernel_launch(void* const* d_in, const int* in_sizes, int n_in,
                              void* d_out, int out_size, void* d_ws, size_t ws_size,
                              hipStream_t stream) {
    const int*   ei   = (const int*)d_in[0];     // int32 from harness
    const float* x    = (const float*)d_in[1];
    const float* Ww   = (const float*)d_in[2];
    const float* Wb   = (const float*)d_in[3];
    const float* aw   = (const float*)d_in[4];
    const float* ab   = (const float*)d_in[5];
    const float* Wo_w = (const float*)d_in[6];
    const float* Wo_b = (const float*)d_in[7];
    float* out = (float*)d_out;

    char* p = (char*)d_ws;
    auto alloc = [&](size_t bytes) -> char* {
        char* q = p;
        p += (bytes + 255) & ~(size_t)255;
        return q;
    };
    uint2*    Wxb      = (uint2*)alloc((size_t)N_NODES * NC * 2);   // bf16 copy
    float*    expagg   = (float*)alloc((size_t)N_NODES * NC * 4);
    float*    Wt       = (float*)alloc((size_t)DX * NC * 4);
    float*    sic      = (float*)alloc((size_t)N_NODES * 4 * 4);
    float*    sjc      = (float*)alloc((size_t)N_NODES * 4 * 4);
    int*      cnt      = (int*)alloc((size_t)N_NODES * 4);
    int*      rowstart = (int*)alloc((size_t)(N_NODES + 1) * 4);
    int*      cursor   = (int*)alloc((size_t)N_NODES * 4);
    int*      csr_src  = (int*)alloc((size_t)(N_EDGES + N_NODES) * 4);
    float*    colsum   = (float*)alloc(NC * 4);
    float*    Ws       = (float*)alloc(NC * DH * 4);

    k_setup<<<(N_NODES + 255) / 256, 256, 0, stream>>>(Ww, Wt, cnt, colsum);
    k_gemm1<<<(N_NODES / 8 + 3) / 4, 256, 0, stream>>>(x, Wt, Wb, aw, ab, Wxb, sic, sjc);
    k_hist<<<1024, 256, 0, stream>>>(ei, cnt);
    k_scan<<<1, 1024, 0, stream>>>(cnt, rowstart, cursor, csr_src);
    k_scatter<<<1024, 256, 0, stream>>>(ei, cursor, csr_src);
    k_aggregate<<<N_NODES / 4, 256, 0, stream>>>(rowstart, csr_src, sic, sjc, Wxb, expagg);
    k_colsum<<<256, 256, 0, stream>>>(expagg, colsum);
    k_prepWs<<<(NC * DH) / 256, 256, 0, stream>>>(Wo_w, colsum, Ws);
    k_out<<<(N_NODES / 8 + 3) / 4, 256, 0, stream>>>(expagg, Ws, Wo_b, out);
}

// Round 6
// 643.045 us; speedup vs baseline: 1.4183x; 1.1752x over previous
//
#include <hip/hip_runtime.h>
#include <cfloat>

#define N_NODES 50000
#define N_EDGES 1600000
#define DX      128
#define DH      64
#define KH      4
#define NC      256                   // KH*DH
#define NEG_SLOPE 0.01f
#define SCAN_BLOCKS 196               // ceil(N_NODES/256)

// ---------- setup: cnt=1 (self-loop pre-count), zero colsum, transpose Ww ----------
__global__ void k_setup(const float* __restrict__ Ww, float* __restrict__ Wt,
                        int* __restrict__ cnt, float* __restrict__ colsum) {
    int i = blockIdx.x * 256 + threadIdx.x;
    if (i < N_NODES) cnt[i] = 1;               // every node gets one self-loop
    if (i < NC) colsum[i] = 0.f;
    if (i < DX * NC) {
        int d = i >> 8, c = i & 255;
        Wt[d * NC + c] = Ww[c * DX + d];
    }
}

__device__ __forceinline__ unsigned pack_bf16(float a, float b) {
    unsigned ua = __float_as_uint(a), ub = __float_as_uint(b);
    ua = (ua + 0x7FFFu + ((ua >> 16) & 1u)) >> 16;          // RNE
    ub = (ub + 0x7FFFu + ((ub >> 16) & 1u)) & 0xFFFF0000u;
    return ua | ub;
}

// ---------- Wx GEMM + fused si/sj epilogue; writes bf16 copy for the gather ----------
__global__ void __launch_bounds__(256) k_gemm1(const float* __restrict__ x,
                                               const float* __restrict__ Wt,
                                               const float* __restrict__ Wb,
                                               const float* __restrict__ aw,
                                               const float* __restrict__ ab,
                                               uint2* __restrict__ Wxb,
                                               float* __restrict__ sic,
                                               float* __restrict__ sjc) {
    int wave = blockIdx.x * 4 + (threadIdx.x >> 6);
    if (wave >= N_NODES / 8) return;           // 50000 % 8 == 0
    int lane = threadIdx.x & 63;
    int kh = lane >> 4, lq = lane & 15;
    int n0 = wave * 8;
    const float4* WtV = (const float4*)Wt;
    float acc[8][4];
#pragma unroll
    for (int r = 0; r < 8; ++r)
#pragma unroll
        for (int q = 0; q < 4; ++q) acc[r][q] = 0.f;

    for (int d = 0; d < DX; d += 4) {
        float xr[8][4];
#pragma unroll
        for (int r = 0; r < 8; ++r) {
            float4 v = *(const float4*)&x[(size_t)(n0 + r) * DX + d];
            xr[r][0] = v.x; xr[r][1] = v.y; xr[r][2] = v.z; xr[r][3] = v.w;
        }
#pragma unroll
        for (int q = 0; q < 4; ++q) {
            float4 wv = WtV[(size_t)(d + q) * 64 + lane];
#pragma unroll
            for (int r = 0; r < 8; ++r) {
                acc[r][0] += xr[r][q] * wv.x;
                acc[r][1] += xr[r][q] * wv.y;
                acc[r][2] += xr[r][q] * wv.z;
                acc[r][3] += xr[r][q] * wv.w;
            }
        }
    }
    float4 bias = ((const float4*)Wb)[lane];
    const float* awi = aw + kh * 2 * DH + lq * 4;
    const float* awj = awi + DH;
    float ai0 = awi[0], ai1 = awi[1], ai2 = awi[2], ai3 = awi[3];
    float aj0 = awj[0], aj1 = awj[1], aj2 = awj[2], aj3 = awj[3];
    float abk = ab[kh];
#pragma unroll
    for (int r = 0; r < 8; ++r) {
        float o0 = acc[r][0] + bias.x, o1 = acc[r][1] + bias.y;
        float o2 = acc[r][2] + bias.z, o3 = acc[r][3] + bias.w;
        uint2 pk; pk.x = pack_bf16(o0, o1); pk.y = pack_bf16(o2, o3);
        Wxb[(size_t)(n0 + r) * 64 + lane] = pk;
        float pi = o0 * ai0 + o1 * ai1 + o2 * ai2 + o3 * ai3;
        float pj = o0 * aj0 + o1 * aj1 + o2 * aj2 + o3 * aj3;
#pragma unroll
        for (int off = 8; off >= 1; off >>= 1) {
            pi += __shfl_xor(pi, off, 64);
            pj += __shfl_xor(pj, off, 64);
        }
        if (lq == 0) {
            sic[(n0 + r) * 4 + kh] = pi + abk;   // fold ab into dst-side score
            sjc[(n0 + r) * 4 + kh] = pj;
        }
    }
}

// ---------- CSR build: real edges only (self loops pre-placed by k_fill) ----------
__global__ void k_hist(const int* __restrict__ ei, int* __restrict__ cnt) {
    const int4* dst4 = (const int4*)(ei + N_EDGES);
    int stride = gridDim.x * blockDim.x;
    for (int e = blockIdx.x * blockDim.x + threadIdx.x; e < N_EDGES / 4; e += stride) {
        int4 d = dst4[e];
        atomicAdd(&cnt[d.x], 1);
        atomicAdd(&cnt[d.y], 1);
        atomicAdd(&cnt[d.z], 1);
        atomicAdd(&cnt[d.w], 1);
    }
}

// ---------- multi-block scan, phase 1: per-block sums ----------
__global__ void __launch_bounds__(256) k_blocksum(const int* __restrict__ cnt,
                                                  int* __restrict__ bsum) {
    __shared__ int part[4];
    int i = blockIdx.x * 256 + threadIdx.x;
    int v = (i < N_NODES) ? cnt[i] : 0;
#pragma unroll
    for (int off = 32; off >= 1; off >>= 1) v += __shfl_down(v, off, 64);
    if ((threadIdx.x & 63) == 0) part[threadIdx.x >> 6] = v;
    __syncthreads();
    if (threadIdx.x == 0)
        bsum[blockIdx.x] = part[0] + part[1] + part[2] + part[3];
}

// ---------- phase 2: scan 196 block sums (1 block) ----------
__global__ void __launch_bounds__(256) k_scanb(const int* __restrict__ bsum,
                                               int* __restrict__ bpre,
                                               int* __restrict__ rowstart) {
    __shared__ int s[256];
    int t = threadIdx.x;
    int v = (t < SCAN_BLOCKS) ? bsum[t] : 0;
    s[t] = v;
    __syncthreads();
#pragma unroll
    for (int off = 1; off < 256; off <<= 1) {
        int u = (t >= off) ? s[t - off] : 0;
        __syncthreads();
        s[t] += u;
        __syncthreads();
    }
    if (t < SCAN_BLOCKS) bpre[t] = s[t] - v;      // exclusive
    if (t == 255) rowstart[N_NODES] = s[255];     // total = ET
}

// ---------- phase 3: in-block scan + write rowstart/cursor/self-loop ----------
__global__ void __launch_bounds__(256) k_fill(const int* __restrict__ cnt,
                                              const int* __restrict__ bpre,
                                              int* __restrict__ rowstart,
                                              int* __restrict__ cursor,
                                              int* __restrict__ csr_src) {
    __shared__ int s[256];
    int t = threadIdx.x;
    int i = blockIdx.x * 256 + t;
    int v = (i < N_NODES) ? cnt[i] : 0;
    s[t] = v;
    __syncthreads();
#pragma unroll
    for (int off = 1; off < 256; off <<= 1) {
        int u = (t >= off) ? s[t - off] : 0;
        __syncthreads();
        s[t] += u;
        __syncthreads();
    }
    if (i < N_NODES) {
        int rs = bpre[blockIdx.x] + s[t] - v;
        rowstart[i] = rs;
        csr_src[rs] = i;           // self-loop edge placed first
        cursor[i] = rs + 1;
    }
}

__global__ void k_scatter(const int* __restrict__ ei, int* __restrict__ cursor,
                          int* __restrict__ csr_src) {
    const int4* src4 = (const int4*)ei;
    const int4* dst4 = (const int4*)(ei + N_EDGES);
    int stride = gridDim.x * blockDim.x;
    for (int e = blockIdx.x * blockDim.x + threadIdx.x; e < N_EDGES / 4; e += stride) {
        int4 sv = src4[e];
        int4 dv = dst4[e];
        csr_src[atomicAdd(&cursor[dv.x], 1)] = sv.x;
        csr_src[atomicAdd(&cursor[dv.y], 1)] = sv.y;
        csr_src[atomicAdd(&cursor[dv.z], 1)] = sv.z;
        csr_src[atomicAdd(&cursor[dv.w], 1)] = sv.w;
    }
}

// ---------- aggregation, software-pipelined x8, pure (no LDS/atomics) ----------
__device__ __forceinline__ void edge_acc(unsigned gx, unsigned gy, float t, float sval,
                                         float& den, float& a0, float& a1, float& a2, float& a3) {
    float e = sval + t;
    e = (e >= 0.f) ? e : NEG_SLOPE * e;
    float ex = __expf(e);
    den += ex;
    a0 += ex * __uint_as_float(gx << 16);
    a1 += ex * __uint_as_float(gx & 0xFFFF0000u);
    a2 += ex * __uint_as_float(gy << 16);
    a3 += ex * __uint_as_float(gy & 0xFFFF0000u);
}

__global__ void __launch_bounds__(256) k_aggregate(const int* __restrict__ rowstart,
                                                   const int* __restrict__ csr_src,
                                                   const float* __restrict__ sic,
                                                   const float* __restrict__ sjc,
                                                   const uint2* __restrict__ Wxb,
                                                   float* __restrict__ expagg) {
    int dst = blockIdx.x * 4 + (threadIdx.x >> 6);   // grid = 12500, exact
    int lane = threadIdx.x & 63;
    int kh = lane >> 4;
    int i0 = rowstart[dst], i1 = rowstart[dst + 1];
    float sval = sic[dst * 4 + kh];

    float den = 0.f, a0 = 0.f, a1 = 0.f, a2 = 0.f, a3 = 0.f;
    int i = i0;
    for (; i + 8 <= i1; i += 8) {
        int s0 = csr_src[i];     int s1 = csr_src[i + 1];
        int s2 = csr_src[i + 2]; int s3 = csr_src[i + 3];
        int s4 = csr_src[i + 4]; int s5 = csr_src[i + 5];
        int s6 = csr_src[i + 6]; int s7 = csr_src[i + 7];
        uint2 g0 = Wxb[(size_t)s0 * 64 + lane];
        uint2 g1 = Wxb[(size_t)s1 * 64 + lane];
        uint2 g2 = Wxb[(size_t)s2 * 64 + lane];
        uint2 g3 = Wxb[(size_t)s3 * 64 + lane];
        uint2 g4 = Wxb[(size_t)s4 * 64 + lane];
        uint2 g5 = Wxb[(size_t)s5 * 64 + lane];
        uint2 g6 = Wxb[(size_t)s6 * 64 + lane];
        uint2 g7 = Wxb[(size_t)s7 * 64 + lane];
        float t0 = sjc[s0 * 4 + kh]; float t1 = sjc[s1 * 4 + kh];
        float t2 = sjc[s2 * 4 + kh]; float t3 = sjc[s3 * 4 + kh];
        float t4 = sjc[s4 * 4 + kh]; float t5 = sjc[s5 * 4 + kh];
        float t6 = sjc[s6 * 4 + kh]; float t7 = sjc[s7 * 4 + kh];
        edge_acc(g0.x, g0.y, t0, sval, den, a0, a1, a2, a3);
        edge_acc(g1.x, g1.y, t1, sval, den, a0, a1, a2, a3);
        edge_acc(g2.x, g2.y, t2, sval, den, a0, a1, a2, a3);
        edge_acc(g3.x, g3.y, t3, sval, den, a0, a1, a2, a3);
        edge_acc(g4.x, g4.y, t4, sval, den, a0, a1, a2, a3);
        edge_acc(g5.x, g5.y, t5, sval, den, a0, a1, a2, a3);
        edge_acc(g6.x, g6.y, t6, sval, den, a0, a1, a2, a3);
        edge_acc(g7.x, g7.y, t7, sval, den, a0, a1, a2, a3);
    }
    for (; i < i1; ++i) {
        int s = csr_src[i];
        uint2 g = Wxb[(size_t)s * 64 + lane];
        float t = sjc[s * 4 + kh];
        edge_acc(g.x, g.y, t, sval, den, a0, a1, a2, a3);
    }
    float r = 1.f / den;
    float4 o;
    o.x = __expf(a0 * r); o.y = __expf(a1 * r);
    o.z = __expf(a2 * r); o.w = __expf(a3 * r);
    ((float4*)expagg)[(size_t)dst * 64 + lane] = o;
}

// ---------- column sums of exp(agg) ----------
__global__ void __launch_bounds__(256) k_colsum(const float* __restrict__ expagg,
                                                float* __restrict__ colsum) {
    int c = threadIdx.x;
    int r0 = blockIdx.x * 196;
    int r1 = min(r0 + 196, N_NODES);
    float s = 0.f;
    for (int r = r0; r < r1; ++r) s += expagg[(size_t)r * NC + c];
    atomicAdd(&colsum[c], s);
}

// ---------- Ws[c][j] = Wo_w[j][c] / colsum[c] ----------
__global__ void k_prepWs(const float* __restrict__ Wo_w, const float* __restrict__ colsum,
                         float* __restrict__ Ws) {
    int i = blockIdx.x * 256 + threadIdx.x;   // 16384 total
    int c = i >> 6, j = i & 63;
    Ws[c * 64 + j] = Wo_w[j * NC + c] / colsum[c];
}

// ---------- out[n][j] = sum_c expagg[n][c] * Ws[c][j] + Wo_b[j] ----------
__global__ void __launch_bounds__(256) k_out(const float* __restrict__ expagg,
                                             const float* __restrict__ Ws,
                                             const float* __restrict__ Wo_b,
                                             float* __restrict__ out) {
    int wave = blockIdx.x * 4 + (threadIdx.x >> 6);
    if (wave >= N_NODES / 8) return;
    int j = threadIdx.x & 63;
    int n0 = wave * 8;
    float acc[8];
#pragma unroll
    for (int r = 0; r < 8; ++r) acc[r] = 0.f;
    for (int c = 0; c < NC; c += 4) {
        float w0 = Ws[c * 64 + j];
        float w1 = Ws[(c + 1) * 64 + j];
        float w2 = Ws[(c + 2) * 64 + j];
        float w3 = Ws[(c + 3) * 64 + j];
#pragma unroll
        for (int r = 0; r < 8; ++r) {
            float4 v = *(const float4*)&expagg[(size_t)(n0 + r) * NC + c];
            acc[r] += v.x * w0 + v.y * w1 + v.z * w2 + v.w * w3;
        }
    }
    float b = Wo_b[j];
#pragma unroll
    for (int r = 0; r < 8; ++r)
        out[(size_t)(n0 + r) * DH + j] = acc[r] + b;
}

extern "C" void kernel_launch(void* const* d_in, const int* in_sizes, int n_in,
                              void* d_out, int out_size, void* d_ws, size_t ws_size,
                              hipStream_t stream) {
    const int*   ei   = (const int*)d_in[0];     // int32 from harness
    const float* x    = (const float*)d_in[1];
    const float* Ww   = (const float*)d_in[2];
    const float* Wb   = (const float*)d_in[3];
    const float* aw   = (const float*)d_in[4];
    const float* ab   = (const float*)d_in[5];
    const float* Wo_w = (const float*)d_in[6];
    const float* Wo_b = (const float*)d_in[7];
    float* out = (float*)d_out;

    char* p = (char*)d_ws;
    auto alloc = [&](size_t bytes) -> char* {
        char* q = p;
        p += (bytes + 255) & ~(size_t)255;
        return q;
    };
    uint2*    Wxb      = (uint2*)alloc((size_t)N_NODES * NC * 2);   // bf16 copy
    float*    expagg   = (float*)alloc((size_t)N_NODES * NC * 4);
    float*    Wt       = (float*)alloc((size_t)DX * NC * 4);
    float*    sic      = (float*)alloc((size_t)N_NODES * 4 * 4);
    float*    sjc      = (float*)alloc((size_t)N_NODES * 4 * 4);
    int*      cnt      = (int*)alloc((size_t)N_NODES * 4);
    int*      rowstart = (int*)alloc((size_t)(N_NODES + 1) * 4);
    int*      cursor   = (int*)alloc((size_t)N_NODES * 4);
    int*      csr_src  = (int*)alloc((size_t)(N_EDGES + N_NODES) * 4);
    float*    colsum   = (float*)alloc(NC * 4);
    float*    Ws       = (float*)alloc(NC * DH * 4);
    int*      bsum     = (int*)alloc(SCAN_BLOCKS * 4);
    int*      bpre     = (int*)alloc(SCAN_BLOCKS * 4);

    k_setup<<<(N_NODES + 255) / 256, 256, 0, stream>>>(Ww, Wt, cnt, colsum);
    k_gemm1<<<(N_NODES / 8 + 3) / 4, 256, 0, stream>>>(x, Wt, Wb, aw, ab, Wxb, sic, sjc);
    k_hist<<<1024, 256, 0, stream>>>(ei, cnt);
    k_blocksum<<<SCAN_BLOCKS, 256, 0, stream>>>(cnt, bsum);
    k_scanb<<<1, 256, 0, stream>>>(bsum, bpre, rowstart);
    k_fill<<<SCAN_BLOCKS, 256, 0, stream>>>(cnt, bpre, rowstart, cursor, csr_src);
    k_scatter<<<1024, 256, 0, stream>>>(ei, cursor, csr_src);
    k_aggregate<<<N_NODES / 4, 256, 0, stream>>>(rowstart, csr_src, sic, sjc, Wxb, expagg);
    k_colsum<<<256, 256, 0, stream>>>(expagg, colsum);
    k_prepWs<<<(NC * DH) / 256, 256, 0, stream>>>(Wo_w, colsum, Ws);
    k_out<<<(N_NODES / 8 + 3) / 4, 256, 0, stream>>>(expagg, Ws, Wo_b, out);
}

// Round 7
// 562.622 us; speedup vs baseline: 1.6210x; 1.1429x over previous
//
#include <hip/hip_runtime.h>
#include <cfloat>

#define N_NODES 50000
#define N_EDGES 1600000
#define DX      128
#define DH      64
#define KH      4
#define NC      256                   // KH*DH
#define NEG_SLOPE 0.01f
#define SCAN_BLOCKS 196               // ceil(N_NODES/256)

// ---------- setup: cnt=1 (self-loop pre-count), zero colsum, transpose Ww ----------
__global__ void k_setup(const float* __restrict__ Ww, float* __restrict__ Wt,
                        int* __restrict__ cnt, float* __restrict__ colsum) {
    int i = blockIdx.x * 256 + threadIdx.x;
    if (i < N_NODES) cnt[i] = 1;               // every node gets one self-loop
    if (i < NC) colsum[i] = 0.f;
    if (i < DX * NC) {
        int d = i >> 8, c = i & 255;
        Wt[d * NC + c] = Ww[c * DX + d];
    }
}

__device__ __forceinline__ unsigned pack_bf16(float a, float b) {
    unsigned ua = __float_as_uint(a), ub = __float_as_uint(b);
    ua = (ua + 0x7FFFu + ((ua >> 16) & 1u)) >> 16;          // RNE
    ub = (ub + 0x7FFFu + ((ub >> 16) & 1u)) & 0xFFFF0000u;
    return ua | ub;
}

// ---------- Wx GEMM + fused si/sj epilogue; writes bf16 copy for the gather ----------
__global__ void __launch_bounds__(256) k_gemm1(const float* __restrict__ x,
                                               const float* __restrict__ Wt,
                                               const float* __restrict__ Wb,
                                               const float* __restrict__ aw,
                                               const float* __restrict__ ab,
                                               uint2* __restrict__ Wxb,
                                               float* __restrict__ sic,
                                               float* __restrict__ sjc) {
    int wave = blockIdx.x * 4 + (threadIdx.x >> 6);
    if (wave >= N_NODES / 8) return;           // 50000 % 8 == 0
    int lane = threadIdx.x & 63;
    int kh = lane >> 4, lq = lane & 15;
    int n0 = wave * 8;
    const float4* WtV = (const float4*)Wt;
    float acc[8][4];
#pragma unroll
    for (int r = 0; r < 8; ++r)
#pragma unroll
        for (int q = 0; q < 4; ++q) acc[r][q] = 0.f;

    for (int d = 0; d < DX; d += 4) {
        float xr[8][4];
#pragma unroll
        for (int r = 0; r < 8; ++r) {
            float4 v = *(const float4*)&x[(size_t)(n0 + r) * DX + d];
            xr[r][0] = v.x; xr[r][1] = v.y; xr[r][2] = v.z; xr[r][3] = v.w;
        }
#pragma unroll
        for (int q = 0; q < 4; ++q) {
            float4 wv = WtV[(size_t)(d + q) * 64 + lane];
#pragma unroll
            for (int r = 0; r < 8; ++r) {
                acc[r][0] += xr[r][q] * wv.x;
                acc[r][1] += xr[r][q] * wv.y;
                acc[r][2] += xr[r][q] * wv.z;
                acc[r][3] += xr[r][q] * wv.w;
            }
        }
    }
    float4 bias = ((const float4*)Wb)[lane];
    const float* awi = aw + kh * 2 * DH + lq * 4;
    const float* awj = awi + DH;
    float ai0 = awi[0], ai1 = awi[1], ai2 = awi[2], ai3 = awi[3];
    float aj0 = awj[0], aj1 = awj[1], aj2 = awj[2], aj3 = awj[3];
    float abk = ab[kh];
#pragma unroll
    for (int r = 0; r < 8; ++r) {
        float o0 = acc[r][0] + bias.x, o1 = acc[r][1] + bias.y;
        float o2 = acc[r][2] + bias.z, o3 = acc[r][3] + bias.w;
        uint2 pk; pk.x = pack_bf16(o0, o1); pk.y = pack_bf16(o2, o3);
        Wxb[(size_t)(n0 + r) * 64 + lane] = pk;
        float pi = o0 * ai0 + o1 * ai1 + o2 * ai2 + o3 * ai3;
        float pj = o0 * aj0 + o1 * aj1 + o2 * aj2 + o3 * aj3;
#pragma unroll
        for (int off = 8; off >= 1; off >>= 1) {
            pi += __shfl_xor(pi, off, 64);
            pj += __shfl_xor(pj, off, 64);
        }
        if (lq == 0) {
            sic[(n0 + r) * 4 + kh] = pi + abk;   // fold ab into dst-side score
            sjc[(n0 + r) * 4 + kh] = pj;
        }
    }
}

// ---------- CSR build: real edges only (self loops pre-placed by k_fill) ----------
__global__ void k_hist(const int* __restrict__ ei, int* __restrict__ cnt) {
    const int4* dst4 = (const int4*)(ei + N_EDGES);
    int stride = gridDim.x * blockDim.x;
    for (int e = blockIdx.x * blockDim.x + threadIdx.x; e < N_EDGES / 4; e += stride) {
        int4 d = dst4[e];
        atomicAdd(&cnt[d.x], 1);
        atomicAdd(&cnt[d.y], 1);
        atomicAdd(&cnt[d.z], 1);
        atomicAdd(&cnt[d.w], 1);
    }
}

// ---------- multi-block scan, phase 1: per-block sums ----------
__global__ void __launch_bounds__(256) k_blocksum(const int* __restrict__ cnt,
                                                  int* __restrict__ bsum) {
    __shared__ int part[4];
    int i = blockIdx.x * 256 + threadIdx.x;
    int v = (i < N_NODES) ? cnt[i] : 0;
#pragma unroll
    for (int off = 32; off >= 1; off >>= 1) v += __shfl_down(v, off, 64);
    if ((threadIdx.x & 63) == 0) part[threadIdx.x >> 6] = v;
    __syncthreads();
    if (threadIdx.x == 0)
        bsum[blockIdx.x] = part[0] + part[1] + part[2] + part[3];
}

// ---------- phase 2: scan 196 block sums (1 block) ----------
__global__ void __launch_bounds__(256) k_scanb(const int* __restrict__ bsum,
                                               int* __restrict__ bpre,
                                               int* __restrict__ rowstart) {
    __shared__ int s[256];
    int t = threadIdx.x;
    int v = (t < SCAN_BLOCKS) ? bsum[t] : 0;
    s[t] = v;
    __syncthreads();
#pragma unroll
    for (int off = 1; off < 256; off <<= 1) {
        int u = (t >= off) ? s[t - off] : 0;
        __syncthreads();
        s[t] += u;
        __syncthreads();
    }
    if (t < SCAN_BLOCKS) bpre[t] = s[t] - v;      // exclusive
    if (t == 255) rowstart[N_NODES] = s[255];     // total = ET
}

// ---------- phase 3: in-block scan + write rowstart/cursor/self-loop ----------
__global__ void __launch_bounds__(256) k_fill(const int* __restrict__ cnt,
                                              const int* __restrict__ bpre,
                                              int* __restrict__ rowstart,
                                              int* __restrict__ cursor,
                                              int* __restrict__ csr_src) {
    __shared__ int s[256];
    int t = threadIdx.x;
    int i = blockIdx.x * 256 + t;
    int v = (i < N_NODES) ? cnt[i] : 0;
    s[t] = v;
    __syncthreads();
#pragma unroll
    for (int off = 1; off < 256; off <<= 1) {
        int u = (t >= off) ? s[t - off] : 0;
        __syncthreads();
        s[t] += u;
        __syncthreads();
    }
    if (i < N_NODES) {
        int rs = bpre[blockIdx.x] + s[t] - v;
        rowstart[i] = rs;
        csr_src[rs] = i;           // self-loop edge placed first
        cursor[i] = rs + 1;
    }
}

__global__ void k_scatter(const int* __restrict__ ei, int* __restrict__ cursor,
                          int* __restrict__ csr_src) {
    const int4* src4 = (const int4*)ei;
    const int4* dst4 = (const int4*)(ei + N_EDGES);
    int stride = gridDim.x * blockDim.x;
    for (int e = blockIdx.x * blockDim.x + threadIdx.x; e < N_EDGES / 4; e += stride) {
        int4 sv = src4[e];
        int4 dv = dst4[e];
        csr_src[atomicAdd(&cursor[dv.x], 1)] = sv.x;
        csr_src[atomicAdd(&cursor[dv.y], 1)] = sv.y;
        csr_src[atomicAdd(&cursor[dv.z], 1)] = sv.z;
        csr_src[atomicAdd(&cursor[dv.w], 1)] = sv.w;
    }
}

// ---------- aggregation, software-pipelined x8, pure (no LDS/atomics) ----------
__device__ __forceinline__ void edge_acc(unsigned gx, unsigned gy, float t, float sval,
                                         float& den, float& a0, float& a1, float& a2, float& a3) {
    float e = sval + t;
    e = (e >= 0.f) ? e : NEG_SLOPE * e;
    float ex = __expf(e);
    den += ex;
    a0 += ex * __uint_as_float(gx << 16);
    a1 += ex * __uint_as_float(gx & 0xFFFF0000u);
    a2 += ex * __uint_as_float(gy << 16);
    a3 += ex * __uint_as_float(gy & 0xFFFF0000u);
}

__global__ void __launch_bounds__(256) k_aggregate(const int* __restrict__ rowstart,
                                                   const int* __restrict__ csr_src,
                                                   const float* __restrict__ sic,
                                                   const float* __restrict__ sjc,
                                                   const uint2* __restrict__ Wxb,
                                                   float* __restrict__ expagg) {
    int dst = blockIdx.x * 4 + (threadIdx.x >> 6);   // grid = 12500, exact
    int lane = threadIdx.x & 63;
    int kh = lane >> 4;
    int i0 = rowstart[dst], i1 = rowstart[dst + 1];
    float sval = sic[dst * 4 + kh];

    float den = 0.f, a0 = 0.f, a1 = 0.f, a2 = 0.f, a3 = 0.f;
    int i = i0;
    for (; i + 8 <= i1; i += 8) {
        int s0 = csr_src[i];     int s1 = csr_src[i + 1];
        int s2 = csr_src[i + 2]; int s3 = csr_src[i + 3];
        int s4 = csr_src[i + 4]; int s5 = csr_src[i + 5];
        int s6 = csr_src[i + 6]; int s7 = csr_src[i + 7];
        uint2 g0 = Wxb[(size_t)s0 * 64 + lane];
        uint2 g1 = Wxb[(size_t)s1 * 64 + lane];
        uint2 g2 = Wxb[(size_t)s2 * 64 + lane];
        uint2 g3 = Wxb[(size_t)s3 * 64 + lane];
        uint2 g4 = Wxb[(size_t)s4 * 64 + lane];
        uint2 g5 = Wxb[(size_t)s5 * 64 + lane];
        uint2 g6 = Wxb[(size_t)s6 * 64 + lane];
        uint2 g7 = Wxb[(size_t)s7 * 64 + lane];
        float t0 = sjc[s0 * 4 + kh]; float t1 = sjc[s1 * 4 + kh];
        float t2 = sjc[s2 * 4 + kh]; float t3 = sjc[s3 * 4 + kh];
        float t4 = sjc[s4 * 4 + kh]; float t5 = sjc[s5 * 4 + kh];
        float t6 = sjc[s6 * 4 + kh]; float t7 = sjc[s7 * 4 + kh];
        edge_acc(g0.x, g0.y, t0, sval, den, a0, a1, a2, a3);
        edge_acc(g1.x, g1.y, t1, sval, den, a0, a1, a2, a3);
        edge_acc(g2.x, g2.y, t2, sval, den, a0, a1, a2, a3);
        edge_acc(g3.x, g3.y, t3, sval, den, a0, a1, a2, a3);
        edge_acc(g4.x, g4.y, t4, sval, den, a0, a1, a2, a3);
        edge_acc(g5.x, g5.y, t5, sval, den, a0, a1, a2, a3);
        edge_acc(g6.x, g6.y, t6, sval, den, a0, a1, a2, a3);
        edge_acc(g7.x, g7.y, t7, sval, den, a0, a1, a2, a3);
    }
    for (; i < i1; ++i) {
        int s = csr_src[i];
        uint2 g = Wxb[(size_t)s * 64 + lane];
        float t = sjc[s * 4 + kh];
        edge_acc(g.x, g.y, t, sval, den, a0, a1, a2, a3);
    }
    float r = 1.f / den;
    float4 o;
    o.x = __expf(a0 * r); o.y = __expf(a1 * r);
    o.z = __expf(a2 * r); o.w = __expf(a3 * r);
    ((float4*)expagg)[(size_t)dst * 64 + lane] = o;
}

// ---------- column sums of exp(agg) ----------
__global__ void __launch_bounds__(256) k_colsum(const float* __restrict__ expagg,
                                                float* __restrict__ colsum) {
    int c = threadIdx.x;
    int r0 = blockIdx.x * 196;
    int r1 = min(r0 + 196, N_NODES);
    float s = 0.f;
    for (int r = r0; r < r1; ++r) s += expagg[(size_t)r * NC + c];
    atomicAdd(&colsum[c], s);
}

// ---------- Ws[c][j] = Wo_w[j][c] / colsum[c] ----------
__global__ void k_prepWs(const float* __restrict__ Wo_w, const float* __restrict__ colsum,
                         float* __restrict__ Ws) {
    int i = blockIdx.x * 256 + threadIdx.x;   // 16384 total
    int c = i >> 6, j = i & 63;
    Ws[c * 64 + j] = Wo_w[j * NC + c] / colsum[c];
}

// ---------- out = expagg @ Ws + b, LDS-tiled ----------
// block: 64 rows x all 64 j. LDS tile padded to 257 -> compute reads bank (n+c)%32.
// lane owns row n, wave owns 16-wide j-group (Ws reads wave-uniform -> scalar).
__global__ void __launch_bounds__(256) k_out(const float* __restrict__ expagg,
                                             const float* __restrict__ Ws,
                                             const float* __restrict__ Wo_b,
                                             float* __restrict__ out) {
    __shared__ float tile[64][257];
    int n0 = blockIdx.x * 64;
    int rows = min(64, N_NODES - n0);
    int tid = threadIdx.x;

    // stage: coalesced float4 loads, 16 independent iterations (MLP)
#pragma unroll
    for (int it = 0; it < 16; ++it) {
        int idx = tid + it * 256;
        if (idx < rows * 64) {
            int row = idx >> 6, c4 = idx & 63;
            float4 v = ((const float4*)expagg)[(size_t)(n0 + row) * 64 + c4];
            tile[row][c4 * 4 + 0] = v.x;
            tile[row][c4 * 4 + 1] = v.y;
            tile[row][c4 * 4 + 2] = v.z;
            tile[row][c4 * 4 + 3] = v.w;
        }
    }
    __syncthreads();

    int nl = tid & 63;
    int j0 = __builtin_amdgcn_readfirstlane((tid >> 6) * 16);   // wave-uniform
    int nr = min(nl, rows - 1);
    float acc[16];
#pragma unroll
    for (int jj = 0; jj < 16; ++jj) acc[jj] = 0.f;

#pragma unroll 4
    for (int c = 0; c < NC; ++c) {
        float av = tile[nr][c];
        const float* wrow = Ws + c * 64 + j0;   // scalar loads (wave-uniform addr)
#pragma unroll
        for (int jj = 0; jj < 16; ++jj) acc[jj] += av * wrow[jj];
    }

    if (nl < rows) {
        float* op = &out[(size_t)(n0 + nl) * DH + j0];
#pragma unroll
        for (int q = 0; q < 4; ++q) {
            float4 o;
            o.x = acc[q * 4 + 0] + Wo_b[j0 + q * 4 + 0];
            o.y = acc[q * 4 + 1] + Wo_b[j0 + q * 4 + 1];
            o.z = acc[q * 4 + 2] + Wo_b[j0 + q * 4 + 2];
            o.w = acc[q * 4 + 3] + Wo_b[j0 + q * 4 + 3];
            *(float4*)(op + q * 4) = o;
        }
    }
}

extern "C" void kernel_launch(void* const* d_in, const int* in_sizes, int n_in,
                              void* d_out, int out_size, void* d_ws, size_t ws_size,
                              hipStream_t stream) {
    const int*   ei   = (const int*)d_in[0];     // int32 from harness
    const float* x    = (const float*)d_in[1];
    const float* Ww   = (const float*)d_in[2];
    const float* Wb   = (const float*)d_in[3];
    const float* aw   = (const float*)d_in[4];
    const float* ab   = (const float*)d_in[5];
    const float* Wo_w = (const float*)d_in[6];
    const float* Wo_b = (const float*)d_in[7];
    float* out = (float*)d_out;

    char* p = (char*)d_ws;
    auto alloc = [&](size_t bytes) -> char* {
        char* q = p;
        p += (bytes + 255) & ~(size_t)255;
        return q;
    };
    uint2*    Wxb      = (uint2*)alloc((size_t)N_NODES * NC * 2);   // bf16 copy
    float*    expagg   = (float*)alloc((size_t)N_NODES * NC * 4);
    float*    Wt       = (float*)alloc((size_t)DX * NC * 4);
    float*    sic      = (float*)alloc((size_t)N_NODES * 4 * 4);
    float*    sjc      = (float*)alloc((size_t)N_NODES * 4 * 4);
    int*      cnt      = (int*)alloc((size_t)N_NODES * 4);
    int*      rowstart = (int*)alloc((size_t)(N_NODES + 1) * 4);
    int*      cursor   = (int*)alloc((size_t)N_NODES * 4);
    int*      csr_src  = (int*)alloc((size_t)(N_EDGES + N_NODES) * 4);
    float*    colsum   = (float*)alloc(NC * 4);
    float*    Ws       = (float*)alloc(NC * DH * 4);
    int*      bsum     = (int*)alloc(SCAN_BLOCKS * 4);
    int*      bpre     = (int*)alloc(SCAN_BLOCKS * 4);

    k_setup<<<(N_NODES + 255) / 256, 256, 0, stream>>>(Ww, Wt, cnt, colsum);
    k_gemm1<<<(N_NODES / 8 + 3) / 4, 256, 0, stream>>>(x, Wt, Wb, aw, ab, Wxb, sic, sjc);
    k_hist<<<1024, 256, 0, stream>>>(ei, cnt);
    k_blocksum<<<SCAN_BLOCKS, 256, 0, stream>>>(cnt, bsum);
    k_scanb<<<1, 256, 0, stream>>>(bsum, bpre, rowstart);
    k_fill<<<SCAN_BLOCKS, 256, 0, stream>>>(cnt, bpre, rowstart, cursor, csr_src);
    k_scatter<<<1024, 256, 0, stream>>>(ei, cursor, csr_src);
    k_aggregate<<<N_NODES / 4, 256, 0, stream>>>(rowstart, csr_src, sic, sjc, Wxb, expagg);
    k_colsum<<<256, 256, 0, stream>>>(expagg, colsum);
    k_prepWs<<<(NC * DH) / 256, 256, 0, stream>>>(Wo_w, colsum, Ws);
    k_out<<<(N_NODES + 63) / 64, 256, 0, stream>>>(expagg, Ws, Wo_b, out);
}